// Round 12
// baseline (406.579 us; speedup 1.0000x reference)
//
#include <hip/hip_runtime.h>

#define NCH 6
#define NX 32
#define PLANE 1024                  // 32x32 cells per x-plane
#define NCELL (NX * PLANE)
#define STEP_STRIDE (NCH * NCELL)   // floats per history slice
#define NTHREADS 256
#define NBLOCKS 128                 // 128*256 = 32768 = one thread per cell
#define RB 2                        // ring slots; (slot, sign-parity) = epoch mod 4

// ws: u64 ring[RB][3][NCELL] SoA streams (stream k = channels 2k,2k+1), then
// int flags. Epoch tag = sign bits (phi in [0,1] post-clip -> sign always 0):
// producer ORs parity P=(e>>1)&1 into both sign bits; (slot=e&1, P) = e mod 4.
// EVERY coupled wave pair (x+-1 planes, adjacent y-rows) is MUTUALLY
// dependent -> skew <= 1 epoch -> only {t, t-2} can occupy a slot; a producer
// can overwrite slot (t&1) only at publish of t+2, which requires consuming
// the reader's t+1 records, which the reader publishes only after its poll-t
// exit -> no read-under-write. Poison 0xAA.. has sign=1 (parity-0 miss) and
// every record is rewritten before its first parity-1 check -> bootstrap-safe.
// R12 change: WAVE-granular dataflow - no __syncthreads, no LDS tile. z+-1
// and intra-wave y neighbor via register shuffles; only 9 u64 ring reads
// per thread per step (batched -> one L3 RT on the critical path).
#define RING_WORDS ((size_t)RB * 3 * NCELL)
#define F_DONE 0

typedef unsigned long long u64;

__device__ __forceinline__ u64 ld64(const u64* p) {
    return __hip_atomic_load(p, __ATOMIC_RELAXED, __HIP_MEMORY_SCOPE_SYSTEM);
}
__device__ __forceinline__ void st64(u64* p, u64 v) {
    __hip_atomic_store(p, v, __ATOMIC_RELAXED, __HIP_MEMORY_SCOPE_SYSTEM);
}
__device__ __forceinline__ int ldi(const int* p) {
    return __hip_atomic_load(p, __ATOMIC_RELAXED, __HIP_MEMORY_SCOPE_SYSTEM);
}
__device__ __forceinline__ void sti(int* p, int v) {
    __hip_atomic_store(p, v, __ATOMIC_RELAXED, __HIP_MEMORY_SCOPE_SYSTEM);
}
__device__ __forceinline__ u64 pack2p(float a, float b, unsigned P) {
    const u64 w = ((u64)__float_as_uint(b) << 32) | __float_as_uint(a);
    return P ? (w | 0x8000000080000000ULL) : w;
}
__device__ __forceinline__ bool tagok(u64 w, unsigned P) {
    return (((unsigned)(w >> 63)) == P) & ((((unsigned)w) >> 31) == P);
}
__device__ __forceinline__ void unpack2(u64 w, float* d0, float* d1) {
    *d0 = __uint_as_float((unsigned)w & 0x7fffffffu);
    *d1 = __uint_as_float((unsigned)(w >> 32) & 0x7fffffffu);
}

__global__ void __launch_bounds__(NTHREADS)
BEMNA_V7_2_PhaseSpace_44117904064519_kernel(
    const float* __restrict__ D,
    const int* __restrict__ sx_p, const int* __restrict__ sy_p,
    const int* __restrict__ sz_p, const int* __restrict__ ex_p,
    const int* __restrict__ ey_p, const int* __restrict__ ez_p,
    const int* __restrict__ maxit_p,
    float* __restrict__ out,
    u64* __restrict__ ring,
    int* __restrict__ flags)
{
    const int tid  = (int)threadIdx.x;
    const int cell = (int)blockIdx.x * NTHREADS + tid;   // linear: wave = 2 y-rows
    const int lane = tid & 63;
    const int x = cell >> 10;
    const int y = (cell >> 5) & 31;
    const int z = cell & 31;

    const int sx = *sx_p, sy = *sy_p, sz = *sz_p;
    const int ex = *ex_p, ey = *ey_p, ez = *ez_p;
    const int maxit = *maxit_p;
    const bool is_seed   = (cell == ((sx << 10) | (sy << 5) | sz));
    const bool is_target = (cell == ((ex << 10) | (ey << 5) | ez));

    // o=0 reads (x-1); o=1 (x+1); o=2 (y-1); o=3 (y+1); o=4 (z-1); o=5 (z+1)
    const int  nbg[NCH] = { cell - PLANE, cell + PLANE, cell - 32, cell + 32, cell - 1, cell + 1 };
    const bool ok[NCH]  = { x >= 1, x <= 30, y >= 1, y <= 30, z >= 1, z <= 30 };

    // ring-read addresses, clamped to own cell at grid edges (value is then
    // masked by the zeroed dreg row; own record always has a valid tag)
    const int cxm = ok[0] ? cell - PLANE : cell;
    const int cxp = ok[1] ? cell + PLANE : cell;
    // external y-side: lane<32 is the even row (needs y-1 from the wave
    // below); lane>=32 is the odd row (needs y+1 from the wave above)
    const bool hi = (lane >= 32);
    const int cye = hi ? (ok[3] ? cell + 32 : cell)
                       : (ok[2] ? cell - 32 : cell);

    // D step-invariant: 36 coefficients in registers (zeroed out-of-bounds)
    float dreg[NCH][NCH];
#pragma unroll
    for (int o = 0; o < NCH; ++o)
#pragma unroll
        for (int i = 0; i < NCH; ++i)
            dreg[o][i] = ok[o] ? D[(size_t)(o * NCH + i) * NCELL + nbg[o]] + 0.95f : 0.0f;

    // ---- init: epoch 0 (slot 0, parity 0 = plain), history slice 0 ----
    float myv[NCH];
    const float iv = is_seed ? 1.0f : 0.0f;
    {
        const u64 p = pack2p(iv, iv, 0);
        st64(&ring[0 * NCELL + cell], p);
        st64(&ring[1 * NCELL + cell], p);
        st64(&ring[2 * NCELL + cell], p);
        float* outp = out + cell;
#pragma unroll
        for (int o = 0; o < NCH; ++o) { myv[o] = iv; outp[o * NCELL] = iv; }
    }

    int tripped = 0;
    // iteration t consumes epoch t, produces phi_{t+1} (= history slice t+1)
    for (int t = 0; t <= maxit - 2; ++t) {
        const u64* r0 = ring + (size_t)(t & 1) * 3 * NCELL;
        const u64* r1 = r0 + NCELL;
        const u64* r2 = r1 + NCELL;
        const unsigned P = (unsigned)((t >> 1) & 1);

        u64 a0, a1, a2, b0, b1, b2, c0, c1, c2;
        int ab = 0;
        for (;;) {
            // 9 batched independent loads -> one waitcnt, one L3 RT per round
            a0 = ld64(r0 + cxm); a1 = ld64(r1 + cxm); a2 = ld64(r2 + cxm);
            b0 = ld64(r0 + cxp); b1 = ld64(r1 + cxp); b2 = ld64(r2 + cxp);
            c0 = ld64(r0 + cye); c1 = ld64(r1 + cye); c2 = ld64(r2 + cye);
            int dn = -1;
            if (lane == 0) dn = ldi(&flags[F_DONE]);   // done duty: 1 load/wave
            dn = __shfl(dn, 0);
            const bool okr = tagok(a0, P) & tagok(a1, P) & tagok(a2, P)
                           & tagok(b0, P) & tagok(b1, P) & tagok(b2, P)
                           & tagok(c0, P) & tagok(c1, P) & tagok(c2, P);
            if (dn >= 0 && t + 1 > dn) { ab = 1; break; }  // wave-uniform abort
            if (__ballot(okr) == ~0ull) break;
            __builtin_amdgcn_s_sleep(1);
        }
        if (ab) break;                     // slices 0..done already written

        float xm[NCH], xp[NCH], ye[NCH];
        unpack2(a0, &xm[0], &xm[1]); unpack2(a1, &xm[2], &xm[3]); unpack2(a2, &xm[4], &xm[5]);
        unpack2(b0, &xp[0], &xp[1]); unpack2(b1, &xp[2], &xp[3]); unpack2(b2, &xp[4], &xp[5]);
        unpack2(c0, &ye[0], &ye[1]); unpack2(c1, &ye[2], &ye[3]); unpack2(c2, &ye[4], &ye[5]);

        // z+-1 and intra-wave y neighbor from register shuffles (edge lanes
        // pull cross-row values -> finite garbage, masked by dreg=0)
        float ym[NCH], yp[NCH], zm[NCH], zp[NCH];
#pragma unroll
        for (int i = 0; i < NCH; ++i) {
            const float yin = __shfl(myv[i], lane ^ 32);
            zm[i] = __shfl(myv[i], (lane - 1) & 63);
            zp[i] = __shfl(myv[i], (lane + 1) & 63);
            ym[i] = hi ? yin : ye[i];
            yp[i] = hi ? ye[i] : yin;
        }

        float v[NCH];
        {
            float s0 = 0.f, s1 = 0.f, s2 = 0.f, s3 = 0.f, s4 = 0.f, s5 = 0.f;
#pragma unroll
            for (int i = 0; i < NCH; ++i) {
                s0 = fmaf(dreg[0][i], xm[i], s0);
                s1 = fmaf(dreg[1][i], xp[i], s1);
                s2 = fmaf(dreg[2][i], ym[i], s2);
                s3 = fmaf(dreg[3][i], yp[i], s3);
                s4 = fmaf(dreg[4][i], zm[i], s4);
                s5 = fmaf(dreg[5][i], zp[i], s5);
            }
            v[0] = fminf(fmaxf(s0, 0.f), 1.f);
            v[1] = fminf(fmaxf(s1, 0.f), 1.f);
            v[2] = fminf(fmaxf(s2, 0.f), 1.f);
            v[3] = fminf(fmaxf(s3, 0.f), 1.f);
            v[4] = fminf(fmaxf(s4, 0.f), 1.f);
            v[5] = fminf(fmaxf(s5, 0.f), 1.f);
        }

        // trip: phi_{t+1} is the frozen state -> done_step = t+1
        if (is_target && !tripped) {
            if (v[0] + v[1] + v[2] + v[3] + v[4] + v[5] > 0.01f) {
                sti(&flags[F_DONE], t + 1);
                tripped = 1;
            }
        }

        // publish epoch t+1: fire-and-forget tagged stores (no drain, no flag)
        {
            const unsigned P1 = (unsigned)(((t + 1) >> 1) & 1);
            u64* w0 = ring + (size_t)((t + 1) & 1) * 3 * NCELL;
            st64(w0 + 0 * NCELL + cell, pack2p(v[0], v[1], P1));
            st64(w0 + 1 * NCELL + cell, pack2p(v[2], v[3], P1));
            st64(w0 + 2 * NCELL + cell, pack2p(v[4], v[5], P1));
        }

        // history slice t+1 last: HBM acks overlap the next poll
        {
            float* outp = out + (size_t)(t + 1) * STEP_STRIDE + cell;
#pragma unroll
            for (int o = 0; o < NCH; ++o) outp[o * NCELL] = v[o];
        }
#pragma unroll
        for (int o = 0; o < NCH; ++o) myv[o] = v[o];
    }
}

// Read-once/write-many fill: one float4 lane per slice element. Each thread
// loads its element of the frozen slice out[tf] once and streams it to
// slices tf+1..maxit-1 (overwriting any stepper overshoot). Write-bound.
__global__ void fill_kernel(const int* __restrict__ flags,
                            float4* __restrict__ out,
                            int total4)
{
    const int s4 = STEP_STRIDE / 4;
    const int maxit = total4 / s4;
    const int ds = flags[F_DONE];
    const int tf = (ds >= 1 && ds <= maxit - 1) ? ds : maxit - 1;
    const int idx = (int)blockIdx.x * (int)blockDim.x + (int)threadIdx.x;
    const float4 v = out[(size_t)tf * s4 + idx];
    for (int t = tf + 1; t < maxit; ++t)
        out[(size_t)t * s4 + idx] = v;
}

extern "C" void kernel_launch(void* const* d_in, const int* in_sizes, int n_in,
                              void* d_out, int out_size, void* d_ws, size_t ws_size,
                              hipStream_t stream)
{
    const float* D   = (const float*)d_in[0];
    const int* sx    = (const int*)d_in[1];
    const int* sy    = (const int*)d_in[2];
    const int* sz    = (const int*)d_in[3];
    const int* ex    = (const int*)d_in[4];
    const int* ey    = (const int*)d_in[5];
    const int* ez    = (const int*)d_in[6];
    const int* maxit = (const int*)d_in[7];
    float* out = (float*)d_out;

    u64* ring  = (u64*)d_ws;                   // 2 x 3 x 32768 x 8B = 1.6 MB
    int* flags = (int*)(ring + RING_WORDS);

    // 128 blocks x 256 threads, one thread per cell, wave-granular dataflow
    // (no intra-block sync). Co-residency by capacity (128 blocks << 256 CUs).
    BEMNA_V7_2_PhaseSpace_44117904064519_kernel<<<dim3(NBLOCKS), dim3(NTHREADS), 0, stream>>>(
        D, sx, sy, sz, ex, ey, ez, maxit, out, ring, flags);

    // one float4 lane per slice element: STEP_STRIDE/4 = 49152 threads
    const int total4 = out_size / 4;
    fill_kernel<<<dim3((STEP_STRIDE / 4) / 256), dim3(256), 0, stream>>>(
        flags, (float4*)out, total4);
}